// Round 5
// baseline (321.451 us; speedup 1.0000x reference)
//
#include <hip/hip_runtime.h>

#define B_ 8
#define T_ 4096
#define E_ 1024
#define K_ 128

typedef __bf16 bf16;
typedef bf16 bf16x8 __attribute__((ext_vector_type(8)));
typedef bf16 bf16x4 __attribute__((ext_vector_type(4)));
typedef float f32x4 __attribute__((ext_vector_type(4)));

// ---------------- K0: convert mu to bf16 ----------------
__global__ __launch_bounds__(256) void k0_cvt_mu(const float* __restrict__ mu,
                                                 bf16* __restrict__ mub) {
    int i = blockIdx.x * 256 + threadIdx.x;
    mub[i] = (bf16)mu[i];
}

// ---------------- KA: fused convert + transpose + att GEMM ----------------
// grid (T/64, B) = 512 blocks, 256 thr (4 waves).
// Per block: 64 t-rows, full E in 4 phases of 256.
//  - load x fp32 -> bf16: write xb, stash in LDS (XOR-swizzled rows)
//  - MFMA: att[k, t-tile] accumulated over e (mu rows from L2)
//  - LDS-transposed writes of xbT
__global__ __launch_bounds__(256) void ka_cvt_att(const float* __restrict__ x,
                                                  const bf16* __restrict__ mub,
                                                  bf16* __restrict__ xb,
                                                  bf16* __restrict__ xbT,
                                                  float* __restrict__ att) {
    const int b = blockIdx.y;
    const int t0 = blockIdx.x * 64;
    const int tid = threadIdx.x;
    const int w = tid >> 6, lane = tid & 63, g = lane >> 4, ln = lane & 15;
    const int tr = tid >> 4, es = tid & 15;
    __shared__ bf16 xs[64][256];   // element (t,e) lives at xs[t][e ^ ((t&7)<<3)]

    f32x4 acc[8];
#pragma unroll
    for (int m = 0; m < 8; ++m) acc[m] = (f32x4){0.f, 0.f, 0.f, 0.f};

    for (int ph = 0; ph < 4; ++ph) {
        const int ep = ph * 256;
        // --- load 64t x 256e, convert, write xb, stash LDS (swizzled) ---
#pragma unroll
        for (int r = 0; r < 4; ++r) {
            const int t = r * 16 + tr;
            const float* src = x + ((size_t)(b * T_ + t0 + t)) * E_ + ep;
            bf16* xbdst = xb + ((size_t)(b * T_ + t0 + t)) * E_ + ep;
#pragma unroll
            for (int q = 0; q < 4; ++q) {
                const int el = es * 4 + q * 64;
                f32x4 v = *(const f32x4*)(src + el);
                bf16x4 o;
                o[0] = (bf16)v[0]; o[1] = (bf16)v[1]; o[2] = (bf16)v[2]; o[3] = (bf16)v[3];
                *(bf16x4*)(xbdst + el) = o;
                *(bf16x4*)&xs[t][el ^ ((t & 7) << 3)] = o;
            }
        }
        __syncthreads();
        // --- MFMA over this phase's e-range ---
        const int tt = w * 16 + ln;
#pragma unroll
        for (int s = 0; s < 8; ++s) {
            bf16x8 bfr = *(const bf16x8*)&xs[tt][(s * 32 + g * 8) ^ ((tt & 7) << 3)];
            const int ecol = ep + s * 32 + g * 8;
#pragma unroll
            for (int m = 0; m < 8; ++m) {
                bf16x8 af = *(const bf16x8*)(mub + (size_t)(m * 16 + ln) * E_ + ecol);
                acc[m] = __builtin_amdgcn_mfma_f32_16x16x32_bf16(af, bfr, acc[m], 0, 0, 0);
            }
        }
        // --- xbT writes (LDS transpose reads) ---
        const int e4 = tid >> 2, ts = tid & 3;
#pragma unroll
        for (int p = 0; p < 4; ++p) {
            const int el = p * 64 + e4;
            bf16* dst = xbT + ((size_t)b * E_ + ep + el) * T_ + t0 + ts * 16;
#pragma unroll
            for (int u = 0; u < 2; ++u) {
                bf16x8 o;
#pragma unroll
                for (int j = 0; j < 8; ++j) {
                    const int t = ts * 16 + u * 8 + j;
                    o[j] = xs[t][el ^ ((t & 7) << 3)];
                }
                *(bf16x8*)(dst + u * 8) = o;
            }
        }
        __syncthreads();
    }
#pragma unroll
    for (int m = 0; m < 8; ++m)
#pragma unroll
        for (int r = 0; r < 4; ++r)
            att[((size_t)b * K_ + m * 16 + g * 4 + r) * T_ + t0 + w * 16 + ln] =
                acc[m][r] * 0.03125f;
}

// ---------------- K2: fused softmax -> attp bf16 ----------------
__global__ __launch_bounds__(256) void k2_softmax(const float* __restrict__ att,
                                                  bf16* __restrict__ attp) {
    const int row = blockIdx.x;   // b*K + k
    const int tid = threadIdx.x;
    const f32x4* p = (const f32x4*)(att + (size_t)row * T_);
    f32x4 v[4];
    float m = -1e30f;
#pragma unroll
    for (int i = 0; i < 4; ++i) {
        v[i] = p[i * 256 + tid];
        m = fmaxf(m, fmaxf(fmaxf(v[i][0], v[i][1]), fmaxf(v[i][2], v[i][3])));
    }
#pragma unroll
    for (int off = 32; off > 0; off >>= 1) m = fmaxf(m, __shfl_xor(m, off));
    __shared__ float redm[4], reds[4];
    const int wave = tid >> 6, lane = tid & 63;
    if (lane == 0) redm[wave] = m;
    __syncthreads();
    m = fmaxf(fmaxf(redm[0], redm[1]), fmaxf(redm[2], redm[3]));
    float s = 0.f;
#pragma unroll
    for (int i = 0; i < 4; ++i) {
        v[i][0] = __expf(v[i][0] - m);
        v[i][1] = __expf(v[i][1] - m);
        v[i][2] = __expf(v[i][2] - m);
        v[i][3] = __expf(v[i][3] - m);
        s += v[i][0] + v[i][1] + v[i][2] + v[i][3];
    }
#pragma unroll
    for (int off = 32; off > 0; off >>= 1) s += __shfl_xor(s, off);
    if (lane == 0) reds[wave] = s;
    __syncthreads();
    const float inv = 1.f / (reds[0] + reds[1] + reds[2] + reds[3]);
    bf16x4* outp = (bf16x4*)(attp + (size_t)row * T_);
#pragma unroll
    for (int i = 0; i < 4; ++i) {
        bf16x4 o;
        o[0] = (bf16)(v[i][0] * inv);
        o[1] = (bf16)(v[i][1] * inv);
        o[2] = (bf16)(v[i][2] * inv);
        o[3] = (bf16)(v[i][3] * inv);
        outp[i * 256 + tid] = o;
    }
}

// ---------------- KC: sel^T[b,e,k] = sum_t xbT[b,e,t]*attp[b,k,t] (full T, fused reduce) ----
// grid (E/16, B) = 512 blocks, 256 thr (4 waves). Wave w: t-chunk [w*1024, +1024).
// A = x^T (16 e-rows x 32 t), B = P^T (32 t x 16 k-cols) -> acc = sel^T[e][k].
__global__ __launch_bounds__(256) void kc_sel(const bf16* __restrict__ xbT,
                                              const bf16* __restrict__ attp,
                                              bf16* __restrict__ selbT) {
    const int eblk = blockIdx.x;
    const int b = blockIdx.y;
    const int tid = threadIdx.x;
    const int w = tid >> 6, lane = tid & 63, g = lane >> 4, ln = lane & 15;
    const int e0 = eblk * 16;

    f32x4 acc[8];
#pragma unroll
    for (int m = 0; m < 8; ++m) acc[m] = (f32x4){0.f, 0.f, 0.f, 0.f};

    const bf16* xrow = xbT + ((size_t)b * E_ + e0 + ln) * T_ + w * 1024 + g * 8;
    const bf16* abase = attp + (size_t)b * K_ * T_ + w * 1024 + g * 8;
#pragma unroll 2
    for (int t0 = 0; t0 < 1024; t0 += 32) {
        bf16x8 af = *(const bf16x8*)(xrow + t0);
#pragma unroll
        for (int m = 0; m < 8; ++m) {
            bf16x8 bfr = *(const bf16x8*)(abase + (size_t)(m * 16 + ln) * T_ + t0);
            acc[m] = __builtin_amdgcn_mfma_f32_16x16x32_bf16(af, bfr, acc[m], 0, 0, 0);
        }
    }
    __shared__ float part[4][16][132];
#pragma unroll
    for (int m = 0; m < 8; ++m)
#pragma unroll
        for (int r = 0; r < 4; ++r)
            part[w][g * 4 + r][m * 16 + ln] = acc[m][r];
    __syncthreads();
    const int e = tid >> 4, ks = tid & 15;
    bf16x8 o;
#pragma unroll
    for (int i = 0; i < 8; ++i) {
        const int kq = ks * 8 + i;
        o[i] = (bf16)(part[0][e][kq] + part[1][e][kq] + part[2][e][kq] + part[3][e][kq]);
    }
    *(bf16x8*)(selbT + ((size_t)b * E_ + e0 + e) * K_ + ks * 8) = o;
}

// ---------------- K5: out = k*(xb + P^T @ sel) + b  (attp staged+transposed in LDS) ----
// grid (T/128, E/64, B) = 4096 blocks, 256 thr (4 waves). Wave: 128 t x 16 e.
__global__ __launch_bounds__(256) void k5_out(const bf16* __restrict__ xb,
                                              const bf16* __restrict__ attp,
                                              const bf16* __restrict__ selbT,
                                              const float* __restrict__ kp,
                                              const float* __restrict__ bp,
                                              float* __restrict__ out) {
    const int b = blockIdx.z;
    const int t0 = blockIdx.x * 128;
    const int tid = threadIdx.x;
    const int w = tid >> 6, lane = tid & 63, g = lane >> 4, ln = lane & 15;
    const int e0 = blockIdx.y * 64 + w * 16;
    const float kk = kp[0], bb = bp[0];
    __shared__ bf16 pT[128][128];   // element (t,k) lives at pT[t][k ^ ((t&7)<<3)]

    // stage attp[b][*][t0..+128] transposed
    const int u = tid & 7;
#pragma unroll
    for (int p = 0; p < 4; ++p) {
        const int k = p * 32 + (tid >> 3);
        const bf16* src = attp + ((size_t)b * K_ + k) * T_ + t0 + u * 16;
#pragma unroll
        for (int h = 0; h < 2; ++h) {
            bf16x8 v = *(const bf16x8*)(src + h * 8);
#pragma unroll
            for (int j = 0; j < 8; ++j) {
                const int t = u * 16 + h * 8 + j;   // t&7 == j
                pT[t][k ^ (j << 3)] = v[j];
            }
        }
    }
    __syncthreads();

    f32x4 acc[8];
#pragma unroll
    for (int m = 0; m < 8; ++m) acc[m] = (f32x4){0.f, 0.f, 0.f, 0.f};

#pragma unroll
    for (int ks = 0; ks < 4; ++ks) {
        const int k0 = ks * 32 + g * 8;
        bf16x8 bfr = *(const bf16x8*)(selbT + ((size_t)b * E_ + e0 + ln) * K_ + k0);
#pragma unroll
        for (int m = 0; m < 8; ++m) {
            const int t = m * 16 + ln;
            bf16x8 af = *(const bf16x8*)&pT[t][k0 ^ ((t & 7) << 3)];
            acc[m] = __builtin_amdgcn_mfma_f32_16x16x32_bf16(af, bfr, acc[m], 0, 0, 0);
        }
    }
#pragma unroll
    for (int m = 0; m < 8; ++m) {
#pragma unroll
        for (int r = 0; r < 4; ++r) {
            const int t = t0 + m * 16 + g * 4 + r;
            const size_t idx = ((size_t)b * T_ + t) * E_ + e0 + ln;
            out[idx] = kk * ((float)xb[idx] + acc[m][r]) + bb;
        }
    }
}

extern "C" void kernel_launch(void* const* d_in, const int* in_sizes, int n_in,
                              void* d_out, int out_size, void* d_ws, size_t ws_size,
                              hipStream_t stream) {
    const float* x  = (const float*)d_in[0];
    const float* mu = (const float*)d_in[1];
    // d_in[2]=bias, d_in[3]=Wr, d_in[4]=Wl are dead code in the reference forward.
    const float* kp = (const float*)d_in[5];
    const float* bp = (const float*)d_in[6];
    float* out = (float*)d_out;

    char* ws = (char*)d_ws;
    bf16*  xb    = (bf16*)(ws);                    //  67,108,864
    bf16*  xbT   = (bf16*)(ws + 67108864);         //  67,108,864
    float* att   = (float*)(ws + 134217728);       //  16,777,216
    bf16*  attp  = (bf16*)(ws + 150994944);        //   8,388,608
    bf16*  selbT = (bf16*)(ws + 159383552);        //   2,097,152
    bf16*  mub   = (bf16*)(ws + 161480704);        //     262,144  (total ~154 MB)

    k0_cvt_mu<<<dim3(512), 256, 0, stream>>>(mu, mub);
    ka_cvt_att<<<dim3(64, 8), 256, 0, stream>>>(x, mub, xb, xbT, att);
    k2_softmax<<<dim3(1024), 256, 0, stream>>>(att, attp);
    kc_sel<<<dim3(64, 8), 256, 0, stream>>>(xbT, attp, selbT);
    k5_out<<<dim3(32, 16, 8), 256, 0, stream>>>(xb, attp, selbT, kp, bp, out);
}